// Round 2
// baseline (68.891 us; speedup 1.0000x reference)
//
#include <hip/hip_runtime.h>

// ProbabilityNoiser: p_t = V diag(exp(lambda*sigma)) V^T p0, B=4096, n=512.
//
// Rate matrix (ones(n,n) - n I)/n has spectrum {-1 x (n-1), 0}, so
//   p_t[b] = e^{l_rest*s} p0[b] + (e^{l_zero*s} - e^{l_rest*s}) (v.p0[b]) v
// with l_rest = eigvals[0], l_zero = eigvals[n-1] (eigh ascending),
// v = eigenvectors[:, n-1]. All read from inputs at runtime — exact algebra
// on the provided eigendecomposition, validated R1 (absmax 1.5e-5 vs 8.4e-5).
//
// R1 evidence: kernel absent from rocprof top-5 (all harness 42.5us fills)
// => per-dispatch < 42.5us; roofline model ~3-6us. This round: remove the
// LDS barrier + scalarize uniform loads (latency trim); if dur_us stays
// ~65us the headline is harness fixed overhead, not kernel time.

constexpr int N = 512;  // NUM_CLASSES (fixed by problem)

__global__ __launch_bounds__(256)
void ProbabilityNoiser_kernel(const float* __restrict__ p0,
                              const float* __restrict__ sigma,
                              const float* __restrict__ eigvals,
                              const float* __restrict__ eigvecs,
                              float* __restrict__ out,
                              int batch)
{
    const int wave = threadIdx.x >> 6;          // 4 waves per block
    const int lane = threadIdx.x & 63;
    const int row  = blockIdx.x * 4 + wave;     // one wave per batch row
    if (row >= batch) return;

    const int col = lane * 8;                   // 64 lanes x 8 floats = 512

    // Issue all VMEM up front; no barrier. p0 row: coalesced 2x float4.
    const float4* prow = reinterpret_cast<const float4*>(p0 + (size_t)row * N + col);
    const float4 a0 = prow[0];
    const float4 a1 = prow[1];

    // v = eigvecs column N-1 (lambda~0 direction), stride-N gather.
    // 1 MB array: HBM on first touch, L1/L2-hit for every later wave.
    float v[8];
#pragma unroll
    for (int j = 0; j < 8; ++j)
        v[j] = eigvecs[(size_t)(col + j) * N + (N - 1)];

    // Wave-uniform scalar loads (readfirstlane => s_load, no VMEM gather).
    const int row_s    = __builtin_amdgcn_readfirstlane(row);
    const float sg     = sigma[row_s];
    const float l_rest = eigvals[0];
    const float l_zero = eigvals[N - 1];

    // v . p0[row]: per-lane partial, 64-lane butterfly reduce.
    float dot = a0.x * v[0] + a0.y * v[1] + a0.z * v[2] + a0.w * v[3]
              + a1.x * v[4] + a1.y * v[5] + a1.z * v[6] + a1.w * v[7];
#pragma unroll
    for (int m = 32; m >= 1; m >>= 1)
        dot += __shfl_xor(dot, m, 64);

    const float s_rest = __expf(l_rest * sg);   // ~exp(-sigma)
    const float s_zero = __expf(l_zero * sg);   // ~1
    const float c      = (s_zero - s_rest) * dot;

    float4 o0, o1;
    o0.x = s_rest * a0.x + c * v[0];
    o0.y = s_rest * a0.y + c * v[1];
    o0.z = s_rest * a0.z + c * v[2];
    o0.w = s_rest * a0.w + c * v[3];
    o1.x = s_rest * a1.x + c * v[4];
    o1.y = s_rest * a1.y + c * v[5];
    o1.z = s_rest * a1.z + c * v[6];
    o1.w = s_rest * a1.w + c * v[7];

    float4* orow = reinterpret_cast<float4*>(out + (size_t)row * N + col);
    orow[0] = o0;
    orow[1] = o1;
}

extern "C" void kernel_launch(void* const* d_in, const int* in_sizes, int n_in,
                              void* d_out, int out_size, void* d_ws, size_t ws_size,
                              hipStream_t stream)
{
    const float* p0      = (const float*)d_in[0];  // [B, N] fp32
    const float* sigma   = (const float*)d_in[1];  // [B]    fp32
    const float* eigvals = (const float*)d_in[2];  // [N]    fp32
    const float* eigvecs = (const float*)d_in[3];  // [N, N] fp32 (row-major)
    float* out = (float*)d_out;                    // [B, N] fp32

    const int batch  = in_sizes[1];                // 4096
    const int blocks = (batch + 3) / 4;            // 4 rows (waves) per block

    ProbabilityNoiser_kernel<<<blocks, 256, 0, stream>>>(
        p0, sigma, eigvals, eigvecs, out, batch);
}